// Round 7
// baseline (282.425 us; speedup 1.0000x reference)
//
#include <hip/hip_runtime.h>

// Problem constants
#define G   128
#define A   100
#define WIN 10
#define FD  16
#define H   128
#define NROWS (G*A)          // 12800
#define K1  (WIN*FD)         // 160

typedef __attribute__((ext_vector_type(8))) short short8;
typedef __attribute__((ext_vector_type(4))) float floatx4;

struct BfPair { short h, l; };

__device__ inline unsigned short f2bf(float f) {   // RNE fp32 -> bf16
    unsigned u = __float_as_uint(f);
    u += 0x7fff + ((u >> 16) & 1);
    return (unsigned short)(u >> 16);
}
__device__ inline float bf2f(unsigned short h) {
    return __uint_as_float(((unsigned)h) << 16);
}
__device__ inline BfPair split1(float v) {
    BfPair p;
    unsigned short hb = f2bf(v);
    p.h = (short)hb;
    p.l = (short)f2bf(v - bf2f(hb));
    return p;
}

// ---------------------------------------------------------------------------
// k_prep: pre-split W1/W2/W3 into bf16 hi/lo planes, layout [n=128][k stride 160].
// ---------------------------------------------------------------------------
__global__ __launch_bounds__(256) void k_prep(const float* __restrict__ W1,
                                              const float* __restrict__ W2,
                                              const float* __restrict__ W3,
                                              short* __restrict__ Wh,
                                              short* __restrict__ Wl) {
    const int b = blockIdx.x, t = threadIdx.x;
    int l, kc;
    const float* Wsrc;
    if (b < 10)      { l = 0; kc = b;      Wsrc = W1; }
    else if (b < 18) { l = 1; kc = b - 10; Wsrc = W2; }
    else             { l = 2; kc = b - 18; Wsrc = W3; }
    short* dh = Wh + l * 128 * 160;
    short* dl = Wl + l * 128 * 160;
    for (int e = t; e < 16 * 128; e += 256) {
        int k = kc * 16 + (e >> 7), n = e & 127;
        BfPair p = split1(Wsrc[(size_t)k * H + n]);
        dh[n * 160 + k] = p.h;
        dl[n * 160 + k] = p.l;
    }
}

// ---------------------------------------------------------------------------
// k_nadj: per-group normalized adjacency -> split-bf16 S planes
//   S[g][i pad 112][j pad 128], zeros outside 100x100. Also zeroes the
//   Y-plane j-pad (j in [96,128), rewritten for j<100 by k_ymm later).
// ---------------------------------------------------------------------------
__global__ __launch_bounds__(256) void k_nadj(const float* __restrict__ x,
                                              short* __restrict__ Sh,
                                              short* __restrict__ Sl,
                                              short* __restrict__ Yh,
                                              short* __restrict__ Yl) {
    __shared__ float xcT[WIN][104];
    __shared__ float invn[A];
    __shared__ float adjs[A][101];
    __shared__ float dinv[A];
    const int g = blockIdx.x;
    const int t = threadIdx.x;

    // zero Y-plane pad for this group
    {
        short8 z8 = (short8)0;
        short* ygh = Yh + (size_t)g * 128 * 128;
        short* ygl = Yl + (size_t)g * 128 * 128;
        for (int e = t; e < 512; e += 256) {
            int n = e >> 2, j = 96 + (e & 3) * 8;
            *(short8*)(ygh + n * 128 + j) = z8;
            *(short8*)(ygl + n * 128 + j) = z8;
        }
    }

    for (int idx = t; idx < A * WIN; idx += 256) {
        int a = idx / WIN, w = idx % WIN;
        xcT[w][a] = x[((g * A + a) * WIN + w) * FD + (FD - 1)];
    }
    __syncthreads();
    if (t < A) {
        float m = 0.f;
        #pragma unroll
        for (int w = 0; w < WIN; w++) m += xcT[w][t];
        m *= (1.0f / WIN);
        float ss = 0.f;
        #pragma unroll
        for (int w = 0; w < WIN; w++) {
            float v = xcT[w][t] - m;
            xcT[w][t] = v;
            ss += v * v;
        }
        invn[t] = rsqrtf(ss);
    }
    __syncthreads();
    for (int tt2 = t; tt2 < 2500; tt2 += 256) {
        int ti = tt2 / 50, tj = tt2 % 50;
        int i0 = 2 * ti, j0v = 2 * tj;
        float d00 = 0.f, d01 = 0.f, d10 = 0.f, d11 = 0.f;
        #pragma unroll
        for (int w = 0; w < WIN; w++) {
            float2 xi = *(const float2*)&xcT[w][i0];
            float2 xj = *(const float2*)&xcT[w][j0v];
            d00 = fmaf(xi.x, xj.x, d00); d01 = fmaf(xi.x, xj.y, d01);
            d10 = fmaf(xi.y, xj.x, d10); d11 = fmaf(xi.y, xj.y, d11);
        }
        float ii0 = invn[i0], ii1 = invn[i0 + 1];
        float ij0 = invn[j0v], ij1 = invn[j0v + 1];
        float e = (ti == tj) ? 1.f : 0.f;
        adjs[i0][j0v]         = 1.f - fabsf(d00 * ii0 * ij0) + e;
        adjs[i0][j0v + 1]     = 1.f - fabsf(d01 * ii0 * ij1);
        adjs[i0 + 1][j0v]     = 1.f - fabsf(d10 * ii1 * ij0);
        adjs[i0 + 1][j0v + 1] = 1.f - fabsf(d11 * ii1 * ij1) + e;
    }
    __syncthreads();
    if (t < A) {
        float s = 0.f;
        for (int j = 0; j < A; j++) s += adjs[t][j];
        dinv[t] = rsqrtf(s);
    }
    __syncthreads();
    short* sh = Sh + (size_t)g * 112 * 128;
    short* sl = Sl + (size_t)g * 112 * 128;
    for (int idx = t; idx < 112 * 128; idx += 256) {
        int i = idx >> 7, k = idx & 127;
        float v = (i < A && k < A) ? dinv[i] * adjs[i][k] * dinv[k] : 0.f;
        BfPair p = split1(v);
        sh[idx] = p.h;
        sl[idx] = p.l;
    }
}

// ---------------------------------------------------------------------------
// k_ymm: Y = X @ W  (phase 1 of a layer). One wave per 16-row m-tile (800
// blocks). No LDS, no barriers. A-frags: direct global (fp32+split for
// layer 1, pre-split Z planes otherwise). B-frags: pre-split W planes.
// Epilogue: scatter Y transposed into per-group planes Y[g][n][j].
// ---------------------------------------------------------------------------
__global__ __launch_bounds__(64) void k_ymm(const float* __restrict__ X1,
                                            const short* __restrict__ Zh,
                                            const short* __restrict__ Zl,
                                            const short* __restrict__ Whg,
                                            const short* __restrict__ Wlg,
                                            short* __restrict__ Yh,
                                            short* __restrict__ Yl, int K) {
    const int mtile = blockIdx.x;
    const int lane = threadIdx.x;
    const int r16 = lane & 15, quad = lane >> 4;
    const int row = mtile * 16 + r16;

    floatx4 acc[8];
    #pragma unroll
    for (int nt = 0; nt < 8; nt++) acc[nt] = (floatx4)0.f;

    const int nch = K >> 5;
    for (int c = 0; c < nch; c++) {
        const int k0 = c << 5;
        short8 ah, al;
        if (K == K1) {
            const float* gp = X1 + (size_t)row * K1 + k0 + quad * 8;
            float4 f0 = *(const float4*)gp;
            float4 f1 = *(const float4*)(gp + 4);
            float v[8] = {f0.x, f0.y, f0.z, f0.w, f1.x, f1.y, f1.z, f1.w};
            #pragma unroll
            for (int i = 0; i < 8; i++) {
                BfPair p = split1(v[i]);
                ah[i] = p.h; al[i] = p.l;
            }
        } else {
            ah = *(const short8*)(Zh + (size_t)row * H + k0 + quad * 8);
            al = *(const short8*)(Zl + (size_t)row * H + k0 + quad * 8);
        }
        #pragma unroll
        for (int nt = 0; nt < 8; nt++) {
            size_t wo = (size_t)(nt * 16 + r16) * 160 + k0 + quad * 8;
            short8 bh = *(const short8*)(Whg + wo);
            short8 bl = *(const short8*)(Wlg + wo);
            acc[nt] = __builtin_amdgcn_mfma_f32_16x16x32_bf16(ah, bh, acc[nt], 0, 0, 0);
            acc[nt] = __builtin_amdgcn_mfma_f32_16x16x32_bf16(ah, bl, acc[nt], 0, 0, 0);
            acc[nt] = __builtin_amdgcn_mfma_f32_16x16x32_bf16(al, bh, acc[nt], 0, 0, 0);
        }
    }

    // epilogue: C/D elem rr of acc[nt] = Y[m = mtile*16+quad*4+rr][n = nt*16+r16]
    #pragma unroll
    for (int rr = 0; rr < 4; rr++) {
        int rm = mtile * 16 + quad * 4 + rr;
        int g = rm / 100, j = rm - g * 100;
        size_t base = (size_t)g * 128 * 128 + j;
        #pragma unroll
        for (int nt = 0; nt < 8; nt++) {
            BfPair p = split1(acc[nt][rr]);
            size_t o = base + (size_t)(nt * 16 + r16) * 128;
            Yh[o] = p.h;
            Yl[o] = p.l;
        }
    }
}

// ---------------------------------------------------------------------------
// k_smm: Z = relu(S @ Y + b)  (phase 2). Grid (G, 7 m-tiles), one wave each.
// All operands direct global pre-split planes; no LDS, no barriers.
// last==0: write split-bf16 Z planes; last==1: write fp32 (conv input).
// ---------------------------------------------------------------------------
__global__ __launch_bounds__(64) void k_smm(const short* __restrict__ Sh,
                                            const short* __restrict__ Sl,
                                            const short* __restrict__ Yh,
                                            const short* __restrict__ Yl,
                                            const float* __restrict__ bias,
                                            short* __restrict__ Zh,
                                            short* __restrict__ Zl,
                                            float* __restrict__ Zf, int last) {
    const int g = blockIdx.x, mt = blockIdx.y;
    const int lane = threadIdx.x;
    const int r16 = lane & 15, quad = lane >> 4;

    floatx4 acc[8];
    #pragma unroll
    for (int nt = 0; nt < 8; nt++) acc[nt] = (floatx4)0.f;

    const short* sgh = Sh + ((size_t)g * 112 + mt * 16 + r16) * 128;
    const short* sgl = Sl + ((size_t)g * 112 + mt * 16 + r16) * 128;
    const short* ygh = Yh + (size_t)g * 128 * 128;
    const short* ygl = Yl + (size_t)g * 128 * 128;

    #pragma unroll
    for (int c = 0; c < 4; c++) {
        const int k0 = c << 5;
        short8 ah = *(const short8*)(sgh + k0 + quad * 8);
        short8 al = *(const short8*)(sgl + k0 + quad * 8);
        #pragma unroll
        for (int nt = 0; nt < 8; nt++) {
            size_t yo = (size_t)(nt * 16 + r16) * 128 + k0 + quad * 8;
            short8 bh = *(const short8*)(ygh + yo);
            short8 bl = *(const short8*)(ygl + yo);
            acc[nt] = __builtin_amdgcn_mfma_f32_16x16x32_bf16(ah, bh, acc[nt], 0, 0, 0);
            acc[nt] = __builtin_amdgcn_mfma_f32_16x16x32_bf16(ah, bl, acc[nt], 0, 0, 0);
            acc[nt] = __builtin_amdgcn_mfma_f32_16x16x32_bf16(al, bh, acc[nt], 0, 0, 0);
        }
    }

    float bv[8];
    #pragma unroll
    for (int nt = 0; nt < 8; nt++) bv[nt] = bias[nt * 16 + r16];

    #pragma unroll
    for (int nt = 0; nt < 8; nt++) {
        int col = nt * 16 + r16;
        #pragma unroll
        for (int rr = 0; rr < 4; rr++) {
            int i = mt * 16 + quad * 4 + rr;
            if (i < A) {
                size_t row = (size_t)g * A + i;
                float v = fmaxf(0.f, acc[nt][rr] + bv[nt]);
                if (last) {
                    Zf[row * H + col] = v;
                } else {
                    BfPair p = split1(v);
                    Zh[row * H + col] = p.h;
                    Zl[row * H + col] = p.l;
                }
            }
        }
    }
}

// ---------------------------------------------------------------------------
// k_conv: fused conv1(1x3)+relu+conv2(1x3). 2 rows x 4 cols per lane;
// weights in LDS [c][8] read as broadcast b128; 800 blocks x 256 thr.
// ---------------------------------------------------------------------------
__device__ inline void load_hh(const float* hr, int q, int j0, float* hh) {
    if (q == 0) {
        float4 a  = *(const float4*)(hr);
        float2 b2 = *(const float2*)(hr + 4);
        hh[0] = 0.f;  hh[1] = 0.f;  hh[2] = a.x;  hh[3] = a.y;
        hh[4] = a.z;  hh[5] = a.w;  hh[6] = b2.x; hh[7] = b2.y;
    } else if (q == 31) {
        float2 b2 = *(const float2*)(hr + 122);
        float4 a  = *(const float4*)(hr + 124);
        hh[0] = b2.x; hh[1] = b2.y; hh[2] = a.x;  hh[3] = a.y;
        hh[4] = a.z;  hh[5] = a.w;  hh[6] = 0.f;  hh[7] = 0.f;
    } else {
        float4 a  = *(const float4*)(hr + j0 - 2);
        float4 b4 = *(const float4*)(hr + j0 + 2);
        hh[0] = a.x;  hh[1] = a.y;  hh[2] = a.z;  hh[3] = a.w;
        hh[4] = b4.x; hh[5] = b4.y; hh[6] = b4.z; hh[7] = b4.w;
    }
}

__global__ __launch_bounds__(256) void k_conv(const float* __restrict__ h3,
                                              const float* __restrict__ cw1,
                                              const float* __restrict__ cb1,
                                              const float* __restrict__ cw2,
                                              const float* __restrict__ cb2,
                                              float* __restrict__ out) {
    __shared__ float wbuf[H][8];     // {w0,w1,w2,b1, v0,v1,v2,0}
    const int t = threadIdx.x;
    if (t < H) {
        *(float4*)&wbuf[t][0] = make_float4(cw1[3 * t], cw1[3 * t + 1], cw1[3 * t + 2], cb1[t]);
        *(float4*)&wbuf[t][4] = make_float4(cw2[3 * t], cw2[3 * t + 1], cw2[3 * t + 2], 0.f);
    }
    __syncthreads();

    const int wave = t >> 6, lane = t & 63;
    const int s = lane >> 5, q = lane & 31;
    const int j0 = q * 4;
    const int base = blockIdx.x * 16 + wave * 4;
    const int ra = base + s;        // rows: this lane handles ra and ra+2
    const int rb = ra + 2;
    const float* hra = h3 + (size_t)ra * H;
    const float* hrb = h3 + (size_t)rb * H;

    float hha[8], hhb[8];
    load_hh(hra, q, j0, hha);
    load_hh(hrb, q, j0, hhb);

    const float mlo = (q == 0)  ? 0.f : 1.f;   // conv2 pad: T[-1]=0
    const float mhi = (q == 31) ? 0.f : 1.f;   // T[128]=0

    float acca[4] = {0.f, 0.f, 0.f, 0.f};
    float accb[4] = {0.f, 0.f, 0.f, 0.f};
    #pragma unroll 2
    for (int c = 0; c < H; c++) {
        float4 wA = *(const float4*)&wbuf[c][0];  // w0,w1,w2,b
        float4 wB = *(const float4*)&wbuf[c][4];  // v0,v1,v2,-
        float ta[6], tb[6];
        #pragma unroll
        for (int m = 0; m < 6; m++) {
            ta[m] = fmaxf(0.f, fmaf(wA.z, hha[m + 2],
                               fmaf(wA.y, hha[m + 1],
                               fmaf(wA.x, hha[m], wA.w))));
            tb[m] = fmaxf(0.f, fmaf(wA.z, hhb[m + 2],
                               fmaf(wA.y, hhb[m + 1],
                               fmaf(wA.x, hhb[m], wA.w))));
        }
        ta[0] *= mlo; ta[5] *= mhi;
        tb[0] *= mlo; tb[5] *= mhi;
        #pragma unroll
        for (int p = 0; p < 4; p++) {
            acca[p] = fmaf(wB.x, ta[p], fmaf(wB.y, ta[p + 1], fmaf(wB.z, ta[p + 2], acca[p])));
            accb[p] = fmaf(wB.x, tb[p], fmaf(wB.y, tb[p + 1], fmaf(wB.z, tb[p + 2], accb[p])));
        }
    }
    const float c2b = cb2[0];
    *(float4*)(out + (size_t)ra * H + j0) =
        make_float4(acca[0] + c2b, acca[1] + c2b, acca[2] + c2b, acca[3] + c2b);
    *(float4*)(out + (size_t)rb * H + j0) =
        make_float4(accb[0] + c2b, accb[1] + c2b, accb[2] + c2b, accb[3] + c2b);
}

// ---------------------------------------------------------------------------
extern "C" void kernel_launch(void* const* d_in, const int* in_sizes, int n_in,
                              void* d_out, int out_size, void* d_ws, size_t ws_size,
                              hipStream_t stream) {
    const float* x   = (const float*)d_in[0];
    const float* W1  = (const float*)d_in[1];
    const float* b1  = (const float*)d_in[2];
    const float* W2  = (const float*)d_in[3];
    const float* b2  = (const float*)d_in[4];
    const float* W3  = (const float*)d_in[5];
    const float* b3  = (const float*)d_in[6];
    const float* cw1 = (const float*)d_in[7];
    const float* cb1 = (const float*)d_in[8];
    const float* cw2 = (const float*)d_in[9];
    const float* cb2 = (const float*)d_in[10];
    float* out = (float*)d_out;

    // ws carve-up (all shorts; 16B-aligned segments)
    short* Sh = (short*)d_ws;                       // G*112*128 = 1,835,008
    short* Sl = Sh + (size_t)G * 112 * 128;
    short* Wh = Sl + (size_t)G * 112 * 128;         // 3*128*160 = 61,440
    short* Wl = Wh + 3 * 128 * 160;
    short* Yh = Wl + 3 * 128 * 160;                 // G*128*128 = 2,097,152
    short* Yl = Yh + (size_t)G * 128 * 128;
    short* Zh = Yl + (size_t)G * 128 * 128;         // NROWS*H = 1,638,400
    short* Zl = Zh + (size_t)NROWS * H;
    // layer-3 fp32 output overlays the (then-dead) Z planes: 2*1.6384M shorts
    float* h3f = (float*)Zh;

    k_prep<<<26, 256, 0, stream>>>(W1, W2, W3, Wh, Wl);
    k_nadj<<<G, 256, 0, stream>>>(x, Sh, Sl, Yh, Yl);

    // layer 1
    k_ymm<<<NROWS / 16, 64, 0, stream>>>(x, Zh, Zl, Wh, Wl, Yh, Yl, K1);
    k_smm<<<dim3(G, 7), 64, 0, stream>>>(Sh, Sl, Yh, Yl, b1, Zh, Zl, h3f, 0);
    // layer 2
    k_ymm<<<NROWS / 16, 64, 0, stream>>>(x, Zh, Zl, Wh + 128 * 160, Wl + 128 * 160, Yh, Yl, H);
    k_smm<<<dim3(G, 7), 64, 0, stream>>>(Sh, Sl, Yh, Yl, b2, Zh, Zl, h3f, 0);
    // layer 3
    k_ymm<<<NROWS / 16, 64, 0, stream>>>(x, Zh, Zl, Wh + 256 * 160, Wl + 256 * 160, Yh, Yl, H);
    k_smm<<<dim3(G, 7), 64, 0, stream>>>(Sh, Sl, Yh, Yl, b3, Zh, Zl, h3f, 1);

    // fused conv1 + relu + conv2
    k_conv<<<NROWS / 16, 256, 0, stream>>>(h3f, cw1, cb1, cw2, cb2, out);
}

// Round 8
// 166.767 us; speedup vs baseline: 1.6935x; 1.6935x over previous
//
#include <hip/hip_runtime.h>

// Problem constants
#define G   128
#define A   100
#define WIN 10
#define FD  16
#define H   128
#define NROWS (G*A)          // 12800
#define K1  (WIN*FD)         // 160

// LDS strides (padded for bank-conflict freedom: stride%32 dwords != 0)
#define SST 136   // S planes [112][SST] shorts
#define YST 136   // Y/Z planes [128][YST] shorts
#define AST 40    // layer-1 X staging [112][AST] shorts
#define H3ST 132  // h3 [100][H3ST] floats

typedef __attribute__((ext_vector_type(8))) short short8;
typedef __attribute__((ext_vector_type(4))) short short4v;
typedef __attribute__((ext_vector_type(4))) float floatx4;

struct BfPair { short h, l; };

__device__ inline unsigned short f2bf(float f) {   // RNE fp32 -> bf16
    unsigned u = __float_as_uint(f);
    u += 0x7fff + ((u >> 16) & 1);
    return (unsigned short)(u >> 16);
}
__device__ inline float bf2f(unsigned short h) {
    return __uint_as_float(((unsigned)h) << 16);
}
__device__ inline BfPair split1(float v) {
    BfPair p;
    unsigned short hb = f2bf(v);
    p.h = (short)hb;
    p.l = (short)f2bf(v - bf2f(hb));
    return p;
}

// ---------------------------------------------------------------------------
// ONE kernel for the whole network. Grid = 256 blocks (2 per group; the two
// halves duplicate nadj+layers — free, LDS forces 1 block/CU — and split the
// conv rows so the conv uses the full machine). 1024 threads = 16 waves.
// No inter-block deps, no workspace, no intermediate global traffic.
// ---------------------------------------------------------------------------
__global__ __launch_bounds__(1024) void k_mega(
    const float* __restrict__ x,
    const float* __restrict__ W1, const float* __restrict__ b1,
    const float* __restrict__ W2, const float* __restrict__ b2,
    const float* __restrict__ W3, const float* __restrict__ b3,
    const float* __restrict__ cw1, const float* __restrict__ cb1,
    const float* __restrict__ cw2, const float* __restrict__ cb2,
    float* __restrict__ out)
{
    __shared__ short Ybuf[2 * 128 * YST];   // 69632 B: Y planes / Z planes / adjs(f32)
    __shared__ short Sbuf[2 * 112 * SST];   // 60928 B: S planes, later h3 (f32)
    __shared__ short Abuf[2 * 112 * AST];   // 17920 B: layer-1 X staging
    __shared__ float wbuf[H][8];            //  4096 B: conv weights
    __shared__ float xcT[WIN][104];         //  4160 B
    __shared__ float invn[A];
    __shared__ float dinv[A];
    // total ~157.5 KB

    short* Yh = Ybuf;            short* Yl = Ybuf + 128 * YST;
    short* Sh = Sbuf;            short* Sl = Sbuf + 112 * SST;
    short* Ah = Abuf;            short* Al = Abuf + 112 * AST;
    float* adjs = (float*)Ybuf;  // [100][101], dead before Y is first written
    float* h3f  = (float*)Sbuf;  // [100][H3ST], written after last S use

    const int g = blockIdx.x >> 1, half = blockIdx.x & 1;
    const int t = threadIdx.x;
    const int wvid = t >> 6, lane = t & 63;
    const int quad = lane >> 4, r16 = lane & 15;

    // ---------------- phase 0: adjacency ----------------
    if (t < H) {   // conv weight pack (used much later)
        *(float4*)&wbuf[t][0] = make_float4(cw1[3*t], cw1[3*t+1], cw1[3*t+2], cb1[t]);
        *(float4*)&wbuf[t][4] = make_float4(cw2[3*t], cw2[3*t+1], cw2[3*t+2], cb2[0]);
    }
    for (int e = t; e < A * WIN; e += 1024) {
        int a = e / WIN, wv = e % WIN;
        xcT[wv][a] = x[((g * A + a) * WIN + wv) * FD + (FD - 1)];
    }
    __syncthreads();
    if (t < A) {
        float m = 0.f;
        #pragma unroll
        for (int wv = 0; wv < WIN; wv++) m += xcT[wv][t];
        m *= (1.0f / WIN);
        float ss = 0.f;
        #pragma unroll
        for (int wv = 0; wv < WIN; wv++) {
            float v = xcT[wv][t] - m;
            xcT[wv][t] = v;
            ss += v * v;
        }
        invn[t] = rsqrtf(ss);
    }
    __syncthreads();
    for (int e = t; e < 2500; e += 1024) {
        int ti = e / 50, tj = e % 50;
        int i0 = 2 * ti, j0v = 2 * tj;
        float d00 = 0.f, d01 = 0.f, d10 = 0.f, d11 = 0.f;
        #pragma unroll
        for (int wv = 0; wv < WIN; wv++) {
            float2 xi = *(const float2*)&xcT[wv][i0];
            float2 xj = *(const float2*)&xcT[wv][j0v];
            d00 = fmaf(xi.x, xj.x, d00); d01 = fmaf(xi.x, xj.y, d01);
            d10 = fmaf(xi.y, xj.x, d10); d11 = fmaf(xi.y, xj.y, d11);
        }
        float ii0 = invn[i0], ii1 = invn[i0 + 1];
        float ij0 = invn[j0v], ij1 = invn[j0v + 1];
        float e2 = (ti == tj) ? 1.f : 0.f;
        adjs[i0 * 101 + j0v]           = 1.f - fabsf(d00 * ii0 * ij0) + e2;
        adjs[i0 * 101 + j0v + 1]       = 1.f - fabsf(d01 * ii0 * ij1);
        adjs[(i0 + 1) * 101 + j0v]     = 1.f - fabsf(d10 * ii1 * ij0);
        adjs[(i0 + 1) * 101 + j0v + 1] = 1.f - fabsf(d11 * ii1 * ij1) + e2;
    }
    __syncthreads();
    if (t < A) {
        float s = 0.f;
        for (int j = 0; j < A; j++) s += adjs[t * 101 + j];
        dinv[t] = rsqrtf(s);
    }
    __syncthreads();
    // S planes: [m<112][k<128], zero outside 100x100 (kills all pad garbage)
    for (int e = t; e < 112 * 64; e += 1024) {
        int m = e >> 6, k2 = (e & 63) * 2;
        float v0 = (m < A && k2 < A)     ? dinv[m] * adjs[m * 101 + k2]     * dinv[k2]     : 0.f;
        float v1 = (m < A && k2 + 1 < A) ? dinv[m] * adjs[m * 101 + k2 + 1] * dinv[k2 + 1] : 0.f;
        BfPair p0 = split1(v0), p1 = split1(v1);
        *(short2*)&Sh[m * SST + k2] = make_short2(p0.h, p1.h);
        *(short2*)&Sl[m * SST + k2] = make_short2(p0.l, p1.l);
    }
    // zero layer-1 A-staging pad rows 100..111 (cols 0..31)
    if (t < 384) {
        int r = 100 + (t >> 5), c = t & 31;
        Ah[r * AST + c] = 0; Al[r * AST + c] = 0;
    }
    __syncthreads();   // adjs dead now
    // zero Y planes k in [112,128) (read by phase B chunk 3, never written by phase A)
    for (int e = t; e < 2048; e += 1024) {
        int n = e >> 4, k = 112 + (e & 15);
        Yh[n * YST + k] = 0; Yl[n * YST + k] = 0;
    }

    // ---------------- 3 GCN layers ----------------
    const int ntA  = wvid & 7;               // phase-A n-tile of this wave
    const int mtlo = (wvid < 8) ? 0 : 4;     // phase-A m-tile range
    const int mcnt = (wvid < 8) ? 4 : 3;
    const int mtB  = wvid >> 1;              // phase-B m-tile (7 => idle)
    const int ntB0 = (wvid & 1) * 4;         // phase-B n-tile base

    for (int layer = 0; layer < 3; layer++) {
        const float* Wg = (layer == 0) ? W1 : (layer == 1) ? W2 : W3;
        const float* bg = (layer == 0) ? b1 : (layer == 1) ? b2 : b3;
        const int nch = (layer == 0) ? 5 : 4;   // K/32

        // ---- phase A: Y = X @ W ----
        floatx4 acc[4];
        #pragma unroll
        for (int i = 0; i < 4; i++) acc[i] = (floatx4)0.f;

        for (int c = 0; c < nch; c++) {
            const int k0 = c << 5;
            // B-frag from fp32 W on the fly (coalesced across r16)
            short8 bh, bl;
            {
                const float* wp = Wg + (size_t)(k0 + quad * 8) * H + ntA * 16 + r16;
                #pragma unroll
                for (int i = 0; i < 8; i++) {
                    BfPair p = split1(wp[(size_t)i * H]);
                    bh[i] = p.h; bl[i] = p.l;
                }
            }
            if (layer == 0) {
                __syncthreads();   // protect Abuf from previous chunk's readers
                if (t < 800) {
                    int r = t >> 3, q = t & 7;
                    float4 f = *(const float4*)(x + (size_t)(g * A + r) * K1 + k0 + q * 4);
                    float v[4] = {f.x, f.y, f.z, f.w};
                    short4v hh, ll;
                    #pragma unroll
                    for (int i = 0; i < 4; i++) {
                        BfPair p = split1(v[i]);
                        hh[i] = p.h; ll[i] = p.l;
                    }
                    *(short4v*)&Ah[r * AST + q * 4] = hh;
                    *(short4v*)&Al[r * AST + q * 4] = ll;
                }
                __syncthreads();
                for (int mi = 0; mi < mcnt; mi++) {
                    int mt = mtlo + mi;
                    short8 ah = *(const short8*)&Ah[(mt * 16 + r16) * AST + quad * 8];
                    short8 al = *(const short8*)&Al[(mt * 16 + r16) * AST + quad * 8];
                    acc[mi] = __builtin_amdgcn_mfma_f32_16x16x32_bf16(ah, bh, acc[mi], 0, 0, 0);
                    acc[mi] = __builtin_amdgcn_mfma_f32_16x16x32_bf16(ah, bl, acc[mi], 0, 0, 0);
                    acc[mi] = __builtin_amdgcn_mfma_f32_16x16x32_bf16(al, bh, acc[mi], 0, 0, 0);
                }
            } else {
                // A-frags straight from Z planes (stored [m][k=n] in Ybuf)
                for (int mi = 0; mi < mcnt; mi++) {
                    int mt = mtlo + mi;
                    short8 ah = *(const short8*)&Yh[(mt * 16 + r16) * YST + k0 + quad * 8];
                    short8 al = *(const short8*)&Yl[(mt * 16 + r16) * YST + k0 + quad * 8];
                    acc[mi] = __builtin_amdgcn_mfma_f32_16x16x32_bf16(ah, bh, acc[mi], 0, 0, 0);
                    acc[mi] = __builtin_amdgcn_mfma_f32_16x16x32_bf16(ah, bl, acc[mi], 0, 0, 0);
                    acc[mi] = __builtin_amdgcn_mfma_f32_16x16x32_bf16(al, bh, acc[mi], 0, 0, 0);
                }
            }
        }
        __syncthreads();   // all Z reads done before Y overwrites the buffer

        // epilogue A: write Y planes [n][k=m]
        for (int mi = 0; mi < mcnt; mi++) {
            int mt = mtlo + mi;
            short4v yh4, yl4;
            #pragma unroll
            for (int rr = 0; rr < 4; rr++) {
                BfPair p = split1(acc[mi][rr]);
                yh4[rr] = p.h; yl4[rr] = p.l;
            }
            int off = (ntA * 16 + r16) * YST + mt * 16 + quad * 4;
            *(short4v*)&Yh[off] = yh4;
            *(short4v*)&Yl[off] = yl4;
        }
        __syncthreads();

        // ---- phase B: Z = relu(S @ Y + b) ----
        floatx4 accB[4];
        #pragma unroll
        for (int i = 0; i < 4; i++) accB[i] = (floatx4)0.f;
        if (mtB < 7) {
            #pragma unroll
            for (int c = 0; c < 4; c++) {
                const int k0 = c << 5;
                short8 ah = *(const short8*)&Sh[(mtB * 16 + r16) * SST + k0 + quad * 8];
                short8 al = *(const short8*)&Sl[(mtB * 16 + r16) * SST + k0 + quad * 8];
                #pragma unroll
                for (int j = 0; j < 4; j++) {
                    int nt = ntB0 + j;
                    short8 yh8 = *(const short8*)&Yh[(nt * 16 + r16) * YST + k0 + quad * 8];
                    short8 yl8 = *(const short8*)&Yl[(nt * 16 + r16) * YST + k0 + quad * 8];
                    accB[j] = __builtin_amdgcn_mfma_f32_16x16x32_bf16(ah, yh8, accB[j], 0, 0, 0);
                    accB[j] = __builtin_amdgcn_mfma_f32_16x16x32_bf16(ah, yl8, accB[j], 0, 0, 0);
                    accB[j] = __builtin_amdgcn_mfma_f32_16x16x32_bf16(al, yh8, accB[j], 0, 0, 0);
                }
            }
        }
        __syncthreads();   // all Y reads (and layer-2 S reads) done before overwrite

        // epilogue B: layers 0/1 -> Z planes (over Ybuf, [m][k=n]);
        //             layer 2   -> h3 fp32 (over Sbuf)
        if (mtB < 7) {
            #pragma unroll
            for (int j = 0; j < 4; j++) {
                int n = (ntB0 + j) * 16 + r16;
                float bv = bg[n];
                #pragma unroll
                for (int rr = 0; rr < 4; rr++) {
                    int m = mtB * 16 + quad * 4 + rr;
                    float v = fmaxf(0.f, accB[j][rr] + bv);
                    if (layer < 2) {
                        BfPair p = split1(v);
                        Yh[m * YST + n] = p.h;
                        Yl[m * YST + n] = p.l;
                    } else if (m < A) {
                        h3f[m * H3ST + n] = v;
                    }
                }
            }
        }
        __syncthreads();
    }

    // ---------------- conv: fused conv1(1x3)+relu+conv2(1x3) ----------------
    // This half's 50 rows; 32 col-lanes x 4 cols per row-slot.
    const int slot = t >> 5, q = t & 31;
    const int j0 = q * 4;
    const float mlo = (q == 0)  ? 0.f : 1.f;   // conv2 pad: T[-1]=0
    const float mhi = (q == 31) ? 0.f : 1.f;   // T[128]=0
    const float c2b = wbuf[0][7];
    #pragma unroll
    for (int it = 0; it < 2; it++) {
        int rl = it * 32 + slot;
        if (rl < 50) {
            int r = half * 50 + rl;
            const float* hr = h3f + (size_t)r * H3ST;
            float hh[8];   // h[j0-2 .. j0+5], zero-padded (conv1 padding)
            if (q == 0) {
                hh[0] = 0.f; hh[1] = 0.f;
                #pragma unroll
                for (int i = 0; i < 6; i++) hh[2 + i] = hr[i];
            } else if (q == 31) {
                #pragma unroll
                for (int i = 0; i < 6; i++) hh[i] = hr[122 + i];
                hh[6] = 0.f; hh[7] = 0.f;
            } else {
                #pragma unroll
                for (int i = 0; i < 8; i++) hh[i] = hr[j0 - 2 + i];
            }
            float acc4[4] = {0.f, 0.f, 0.f, 0.f};
            #pragma unroll 4
            for (int c = 0; c < H; c++) {
                float4 wA = *(const float4*)&wbuf[c][0];  // w0,w1,w2,b1
                float4 wB = *(const float4*)&wbuf[c][4];  // v0,v1,v2,cb2
                float tt[6];
                #pragma unroll
                for (int m2 = 0; m2 < 6; m2++)
                    tt[m2] = fmaxf(0.f, fmaf(wA.z, hh[m2 + 2],
                                        fmaf(wA.y, hh[m2 + 1],
                                        fmaf(wA.x, hh[m2], wA.w))));
                tt[0] *= mlo; tt[5] *= mhi;
                #pragma unroll
                for (int p2 = 0; p2 < 4; p2++)
                    acc4[p2] = fmaf(wB.x, tt[p2],
                               fmaf(wB.y, tt[p2 + 1],
                               fmaf(wB.z, tt[p2 + 2], acc4[p2])));
            }
            *(float4*)(out + ((size_t)g * A + r) * H + j0) =
                make_float4(acc4[0] + c2b, acc4[1] + c2b, acc4[2] + c2b, acc4[3] + c2b);
        }
    }
}

// ---------------------------------------------------------------------------
extern "C" void kernel_launch(void* const* d_in, const int* in_sizes, int n_in,
                              void* d_out, int out_size, void* d_ws, size_t ws_size,
                              hipStream_t stream) {
    const float* x   = (const float*)d_in[0];
    const float* W1  = (const float*)d_in[1];
    const float* b1  = (const float*)d_in[2];
    const float* W2  = (const float*)d_in[3];
    const float* b2  = (const float*)d_in[4];
    const float* W3  = (const float*)d_in[5];
    const float* b3  = (const float*)d_in[6];
    const float* cw1 = (const float*)d_in[7];
    const float* cb1 = (const float*)d_in[8];
    const float* cw2 = (const float*)d_in[9];
    const float* cb2 = (const float*)d_in[10];
    float* out = (float*)d_out;

    k_mega<<<G * 2, 1024, 0, stream>>>(x, W1, b1, W2, b2, W3, b3,
                                       cw1, cb1, cw2, cb2, out);
}

// Round 9
// 162.513 us; speedup vs baseline: 1.7379x; 1.0262x over previous
//
#include <hip/hip_runtime.h>

// Problem constants
#define G   128
#define A   100
#define WIN 10
#define FD  16
#define H   128
#define NROWS (G*A)          // 12800
#define K1  (WIN*FD)         // 160

// LDS strides
#define SST 136   // S planes [112][SST] shorts
#define YST 136   // Y/Z planes [128][YST] shorts
#define AST 40    // layer-1 X staging [112][AST] shorts
#define H3ST 132  // h3 [100][H3ST] floats

typedef __attribute__((ext_vector_type(8))) short short8;
typedef __attribute__((ext_vector_type(4))) short short4v;
typedef __attribute__((ext_vector_type(4))) float floatx4;
typedef __attribute__((ext_vector_type(2))) float pf2;   // packed f32 pair

struct BfPair { short h, l; };

__device__ inline unsigned short f2bf(float f) {   // RNE fp32 -> bf16
    unsigned u = __float_as_uint(f);
    u += 0x7fff + ((u >> 16) & 1);
    return (unsigned short)(u >> 16);
}
__device__ inline float bf2f(unsigned short h) {
    return __uint_as_float(((unsigned)h) << 16);
}
__device__ inline BfPair split1(float v) {
    BfPair p;
    unsigned short hb = f2bf(v);
    p.h = (short)hb;
    p.l = (short)f2bf(v - bf2f(hb));
    return p;
}

// ---------------------------------------------------------------------------
// k_prep: pre-split W1/W2/W3 into bf16 hi/lo planes, layout [n=128][k stride 160].
// ---------------------------------------------------------------------------
__global__ __launch_bounds__(256) void k_prep(const float* __restrict__ W1,
                                              const float* __restrict__ W2,
                                              const float* __restrict__ W3,
                                              short* __restrict__ Wh,
                                              short* __restrict__ Wl) {
    const int b = blockIdx.x, t = threadIdx.x;
    int l, kc;
    const float* Wsrc;
    if (b < 10)      { l = 0; kc = b;      Wsrc = W1; }
    else if (b < 18) { l = 1; kc = b - 10; Wsrc = W2; }
    else             { l = 2; kc = b - 18; Wsrc = W3; }
    short* dh = Wh + l * 128 * 160;
    short* dl = Wl + l * 128 * 160;
    for (int e = t; e < 16 * 128; e += 256) {
        int k = kc * 16 + (e >> 7), n = e & 127;
        BfPair p = split1(Wsrc[(size_t)k * H + n]);
        dh[n * 160 + k] = p.h;
        dl[n * 160 + k] = p.l;
    }
}

// ---------------------------------------------------------------------------
// k_mega: whole network, one block per (group, half). 1024 threads = 16 waves.
// ---------------------------------------------------------------------------
__global__ __launch_bounds__(1024) void k_mega(
    const float* __restrict__ x,
    const short* __restrict__ Whg, const short* __restrict__ Wlg,
    const float* __restrict__ b1, const float* __restrict__ b2,
    const float* __restrict__ b3,
    const float* __restrict__ cw1, const float* __restrict__ cb1,
    const float* __restrict__ cw2, const float* __restrict__ cb2,
    float* __restrict__ out)
{
    __shared__ short Ybuf[2 * 128 * YST];   // 69632 B: Y/Z planes; adjs(f32) early
    __shared__ short Sbuf[2 * 112 * SST];   // 60928 B: S planes, later h3 (f32)
    __shared__ short Abuf[2 * 112 * AST];   // 17920 B: layer-1 X staging
    __shared__ float wp2[64][16];           //  4096 B: conv weights, c-pair packed
    __shared__ float xcT[WIN][104];         //  4160 B
    __shared__ float invn[A];
    __shared__ float dinv[A];

    short* Yh = Ybuf;            short* Yl = Ybuf + 128 * YST;
    short* Sh = Sbuf;            short* Sl = Sbuf + 112 * SST;
    short* Ah = Abuf;            short* Al = Abuf + 112 * AST;
    float* adjs = (float*)Ybuf;  // [100][101], dead before Y is first written
    float* h3f  = (float*)Sbuf;  // [100][H3ST], written after last S use

    const int g = blockIdx.x >> 1, half = blockIdx.x & 1;
    const int t = threadIdx.x;
    const int wvid = t >> 6, lane = t & 63;
    const int quad = lane >> 4, r16 = lane & 15;

    // ---------------- phase 0: adjacency + conv weight pack ----------------
    if (t < H) {
        int cp = t >> 1, par = t & 1;
        wp2[cp][0  + par] = cw1[3 * t];
        wp2[cp][2  + par] = cw1[3 * t + 1];
        wp2[cp][4  + par] = cw1[3 * t + 2];
        wp2[cp][6  + par] = cb1[t];
        wp2[cp][8  + par] = cw2[3 * t];
        wp2[cp][10 + par] = cw2[3 * t + 1];
        wp2[cp][12 + par] = cw2[3 * t + 2];
        wp2[cp][14 + par] = cb2[0];
    }
    for (int e = t; e < A * WIN; e += 1024) {
        int a = e / WIN, wv = e % WIN;
        xcT[wv][a] = x[((g * A + a) * WIN + wv) * FD + (FD - 1)];
    }
    __syncthreads();
    if (t < A) {
        float m = 0.f;
        #pragma unroll
        for (int wv = 0; wv < WIN; wv++) m += xcT[wv][t];
        m *= (1.0f / WIN);
        float ss = 0.f;
        #pragma unroll
        for (int wv = 0; wv < WIN; wv++) {
            float v = xcT[wv][t] - m;
            xcT[wv][t] = v;
            ss += v * v;
        }
        invn[t] = rsqrtf(ss);
    }
    __syncthreads();
    for (int e = t; e < 2500; e += 1024) {
        int ti = e / 50, tj = e % 50;
        int i0 = 2 * ti, j0v = 2 * tj;
        float d00 = 0.f, d01 = 0.f, d10 = 0.f, d11 = 0.f;
        #pragma unroll
        for (int wv = 0; wv < WIN; wv++) {
            float2 xi = *(const float2*)&xcT[wv][i0];
            float2 xj = *(const float2*)&xcT[wv][j0v];
            d00 = fmaf(xi.x, xj.x, d00); d01 = fmaf(xi.x, xj.y, d01);
            d10 = fmaf(xi.y, xj.x, d10); d11 = fmaf(xi.y, xj.y, d11);
        }
        float ii0 = invn[i0], ii1 = invn[i0 + 1];
        float ij0 = invn[j0v], ij1 = invn[j0v + 1];
        float e2 = (ti == tj) ? 1.f : 0.f;
        adjs[i0 * 101 + j0v]           = 1.f - fabsf(d00 * ii0 * ij0) + e2;
        adjs[i0 * 101 + j0v + 1]       = 1.f - fabsf(d01 * ii0 * ij1);
        adjs[(i0 + 1) * 101 + j0v]     = 1.f - fabsf(d10 * ii1 * ij0);
        adjs[(i0 + 1) * 101 + j0v + 1] = 1.f - fabsf(d11 * ii1 * ij1) + e2;
    }
    __syncthreads();
    if (t < A) {
        float s = 0.f;
        for (int j = 0; j < A; j++) s += adjs[t * 101 + j];
        dinv[t] = rsqrtf(s);
    }
    __syncthreads();
    // S planes: [m<112][k<128], zero outside 100x100
    for (int e = t; e < 112 * 64; e += 1024) {
        int m = e >> 6, k2 = (e & 63) * 2;
        float v0 = (m < A && k2 < A)     ? dinv[m] * adjs[m * 101 + k2]     * dinv[k2]     : 0.f;
        float v1 = (m < A && k2 + 1 < A) ? dinv[m] * adjs[m * 101 + k2 + 1] * dinv[k2 + 1] : 0.f;
        BfPair p0 = split1(v0), p1 = split1(v1);
        *(short2*)&Sh[m * SST + k2] = make_short2(p0.h, p1.h);
        *(short2*)&Sl[m * SST + k2] = make_short2(p0.l, p1.l);
    }
    // zero layer-1 A-staging pad rows 100..111
    if (t < 384) {
        int r = 100 + (t >> 5), c = t & 31;
        Ah[r * AST + c] = 0; Al[r * AST + c] = 0;
    }
    __syncthreads();   // adjs dead now
    // zero Y planes k in [112,128)
    for (int e = t; e < 2048; e += 1024) {
        int n = e >> 4, k = 112 + (e & 15);
        Yh[n * YST + k] = 0; Yl[n * YST + k] = 0;
    }

    // ---------------- 3 GCN layers ----------------
    const int ntA  = wvid & 7;
    const int mtlo = (wvid < 8) ? 0 : 4;
    const int mcnt = (wvid < 8) ? 4 : 3;
    const int mtB  = wvid >> 1;
    const int ntB0 = (wvid & 1) * 4;

    for (int layer = 0; layer < 3; layer++) {
        const float* bg = (layer == 0) ? b1 : (layer == 1) ? b2 : b3;
        const short* wh = Whg + layer * 128 * 160;
        const short* wl = Wlg + layer * 128 * 160;
        const int nch = (layer == 0) ? 5 : 4;   // K/32

        // ---- phase A: Y = X @ W ----
        floatx4 acc[4];
        #pragma unroll
        for (int i = 0; i < 4; i++) acc[i] = (floatx4)0.f;

        for (int c = 0; c < nch; c++) {
            const int k0 = c << 5;
            // B-frag from pre-split global planes (L2-hot)
            size_t wo = (size_t)(ntA * 16 + r16) * 160 + k0 + quad * 8;
            short8 bh = *(const short8*)(wh + wo);
            short8 bl = *(const short8*)(wl + wo);
            if (layer == 0) {
                __syncthreads();   // protect Abuf from previous chunk's readers
                if (t < 800) {
                    int r = t >> 3, q = t & 7;
                    float4 f = *(const float4*)(x + (size_t)(g * A + r) * K1 + k0 + q * 4);
                    float v[4] = {f.x, f.y, f.z, f.w};
                    short4v hh, ll;
                    #pragma unroll
                    for (int i = 0; i < 4; i++) {
                        BfPair p = split1(v[i]);
                        hh[i] = p.h; ll[i] = p.l;
                    }
                    *(short4v*)&Ah[r * AST + q * 4] = hh;
                    *(short4v*)&Al[r * AST + q * 4] = ll;
                }
                __syncthreads();
                for (int mi = 0; mi < mcnt; mi++) {
                    int mt = mtlo + mi;
                    short8 ah = *(const short8*)&Ah[(mt * 16 + r16) * AST + quad * 8];
                    short8 al = *(const short8*)&Al[(mt * 16 + r16) * AST + quad * 8];
                    acc[mi] = __builtin_amdgcn_mfma_f32_16x16x32_bf16(ah, bh, acc[mi], 0, 0, 0);
                    acc[mi] = __builtin_amdgcn_mfma_f32_16x16x32_bf16(ah, bl, acc[mi], 0, 0, 0);
                    acc[mi] = __builtin_amdgcn_mfma_f32_16x16x32_bf16(al, bh, acc[mi], 0, 0, 0);
                }
            } else {
                for (int mi = 0; mi < mcnt; mi++) {
                    int mt = mtlo + mi;
                    short8 ah = *(const short8*)&Yh[(mt * 16 + r16) * YST + k0 + quad * 8];
                    short8 al = *(const short8*)&Yl[(mt * 16 + r16) * YST + k0 + quad * 8];
                    acc[mi] = __builtin_amdgcn_mfma_f32_16x16x32_bf16(ah, bh, acc[mi], 0, 0, 0);
                    acc[mi] = __builtin_amdgcn_mfma_f32_16x16x32_bf16(ah, bl, acc[mi], 0, 0, 0);
                    acc[mi] = __builtin_amdgcn_mfma_f32_16x16x32_bf16(al, bh, acc[mi], 0, 0, 0);
                }
            }
        }
        __syncthreads();   // all Z reads done before Y overwrites the buffer

        // epilogue A: write Y planes [n][k=m]
        for (int mi = 0; mi < mcnt; mi++) {
            int mt = mtlo + mi;
            short4v yh4, yl4;
            #pragma unroll
            for (int rr = 0; rr < 4; rr++) {
                BfPair p = split1(acc[mi][rr]);
                yh4[rr] = p.h; yl4[rr] = p.l;
            }
            int off = (ntA * 16 + r16) * YST + mt * 16 + quad * 4;
            *(short4v*)&Yh[off] = yh4;
            *(short4v*)&Yl[off] = yl4;
        }
        __syncthreads();

        // ---- phase B: Z = relu(S @ Y + b) ----
        floatx4 accB[4];
        #pragma unroll
        for (int i = 0; i < 4; i++) accB[i] = (floatx4)0.f;
        if (mtB < 7) {
            #pragma unroll
            for (int c = 0; c < 4; c++) {
                const int k0 = c << 5;
                short8 ah = *(const short8*)&Sh[(mtB * 16 + r16) * SST + k0 + quad * 8];
                short8 al = *(const short8*)&Sl[(mtB * 16 + r16) * SST + k0 + quad * 8];
                #pragma unroll
                for (int j = 0; j < 4; j++) {
                    int nt = ntB0 + j;
                    short8 yh8 = *(const short8*)&Yh[(nt * 16 + r16) * YST + k0 + quad * 8];
                    short8 yl8 = *(const short8*)&Yl[(nt * 16 + r16) * YST + k0 + quad * 8];
                    accB[j] = __builtin_amdgcn_mfma_f32_16x16x32_bf16(ah, yh8, accB[j], 0, 0, 0);
                    accB[j] = __builtin_amdgcn_mfma_f32_16x16x32_bf16(ah, yl8, accB[j], 0, 0, 0);
                    accB[j] = __builtin_amdgcn_mfma_f32_16x16x32_bf16(al, yh8, accB[j], 0, 0, 0);
                }
            }
        }
        __syncthreads();   // all Y reads done before overwrite

        if (mtB < 7) {
            #pragma unroll
            for (int j = 0; j < 4; j++) {
                int n = (ntB0 + j) * 16 + r16;
                float bv = bg[n];
                #pragma unroll
                for (int rr = 0; rr < 4; rr++) {
                    int m = mtB * 16 + quad * 4 + rr;
                    float v = fmaxf(0.f, accB[j][rr] + bv);
                    if (layer < 2) {
                        BfPair p = split1(v);
                        Yh[m * YST + n] = p.h;
                        Yl[m * YST + n] = p.l;
                    } else if (m < A) {
                        h3f[m * H3ST + n] = v;
                    }
                }
            }
        }
        __syncthreads();
    }

    // ---------------- conv: fused conv1+relu+conv2, packed c-pairs ----------
    // 8 cols/lane: 50 rows x 16 col-groups = 800 active threads.
    if (t < 800) {
        const int row = t >> 4, q = t & 15;
        const int j0 = q * 8;
        const int r = half * 50 + row;
        const float* hr = h3f + (size_t)r * H3ST;

        float hh[12];   // h[j0-2 .. j0+9], zero-padded (conv1 padding)
        if (q == 0) {
            hh[0] = 0.f; hh[1] = 0.f;
            #pragma unroll
            for (int i = 0; i < 10; i++) hh[2 + i] = hr[i];
        } else if (q == 15) {
            #pragma unroll
            for (int i = 0; i < 10; i++) hh[i] = hr[118 + i];
            hh[10] = 0.f; hh[11] = 0.f;
        } else {
            #pragma unroll
            for (int i = 0; i < 12; i++) hh[i] = hr[j0 - 2 + i];
        }
        const pf2 mlo2 = (pf2)((q == 0)  ? 0.f : 1.f);  // conv2 pad: T[-1]=0
        const pf2 mhi2 = (pf2)((q == 15) ? 0.f : 1.f);  // T[128]=0
        const pf2 zero2 = (pf2)0.f;

        pf2 accp[8];
        #pragma unroll
        for (int p = 0; p < 8; p++) accp[p] = zero2;

        #pragma unroll 2
        for (int cp = 0; cp < 64; cp++) {
            pf2 w0 = *(const pf2*)&wp2[cp][0];
            pf2 w1 = *(const pf2*)&wp2[cp][2];
            pf2 w2 = *(const pf2*)&wp2[cp][4];
            pf2 bb = *(const pf2*)&wp2[cp][6];
            pf2 v0 = *(const pf2*)&wp2[cp][8];
            pf2 v1 = *(const pf2*)&wp2[cp][10];
            pf2 v2 = *(const pf2*)&wp2[cp][12];
            pf2 tt[10];
            #pragma unroll
            for (int m = 0; m < 10; m++) {
                pf2 s = __builtin_elementwise_fma(w2, (pf2)hh[m + 2],
                        __builtin_elementwise_fma(w1, (pf2)hh[m + 1],
                        __builtin_elementwise_fma(w0, (pf2)hh[m], bb)));
                tt[m] = __builtin_elementwise_max(s, zero2);
            }
            tt[0] *= mlo2;
            tt[9] *= mhi2;
            #pragma unroll
            for (int p = 0; p < 8; p++)
                accp[p] = __builtin_elementwise_fma(v0, tt[p],
                          __builtin_elementwise_fma(v1, tt[p + 1],
                          __builtin_elementwise_fma(v2, tt[p + 2], accp[p])));
        }
        const float c2b = wp2[0][14];
        float o[8];
        #pragma unroll
        for (int p = 0; p < 8; p++) o[p] = accp[p].x + accp[p].y + c2b;
        float* op = out + ((size_t)g * A + r) * H + j0;
        *(float4*)op       = make_float4(o[0], o[1], o[2], o[3]);
        *(float4*)(op + 4) = make_float4(o[4], o[5], o[6], o[7]);
    }
}

// ---------------------------------------------------------------------------
extern "C" void kernel_launch(void* const* d_in, const int* in_sizes, int n_in,
                              void* d_out, int out_size, void* d_ws, size_t ws_size,
                              hipStream_t stream) {
    const float* x   = (const float*)d_in[0];
    const float* W1  = (const float*)d_in[1];
    const float* b1  = (const float*)d_in[2];
    const float* W2  = (const float*)d_in[3];
    const float* b2  = (const float*)d_in[4];
    const float* W3  = (const float*)d_in[5];
    const float* b3  = (const float*)d_in[6];
    const float* cw1 = (const float*)d_in[7];
    const float* cb1 = (const float*)d_in[8];
    const float* cw2 = (const float*)d_in[9];
    const float* cb2 = (const float*)d_in[10];
    float* out = (float*)d_out;

    short* Wh = (short*)d_ws;              // 3*128*160 shorts
    short* Wl = Wh + 3 * 128 * 160;

    k_prep<<<26, 256, 0, stream>>>(W1, W2, W3, Wh, Wl);
    k_mega<<<G * 2, 1024, 0, stream>>>(x, Wh, Wl, b1, b2, b3,
                                       cw1, cb1, cw2, cb2, out);
}